// Round 2
// baseline (16277.757 us; speedup 1.0000x reference)
//
#include <hip/hip_runtime.h>
#include <hip/hip_bf16.h>
#include <math.h>

// EquiformerV2 block, fp32, workspace-lean decomposition.
// E=40000 edges, N=2000 nodes, C=64, L2=25, M2=19, NL=2.

#define NRBF 600
#define DIN 728
#define GPTS 288

__constant__ int d_mg[19] = {0,1,0,1,2,1,0,1,2,2,1,0,1,2,2,1,0,1,2};
__constant__ int d_loc[25] = {0,1,1,1,2,2,2,2,2,3,3,3,3,3,3,3,4,4,4,4,4,4,4,4,4};
__constant__ int d_gm[3][8] = {{0,2,6,11,16,-1,-1,-1},{1,3,5,7,10,12,15,17},{4,8,9,13,14,18,-1,-1}};
__constant__ int d_gcnt[3] = {5,8,6};

__device__ inline float silu_f(float v){ return v/(1.0f+__expf(-v)); }

__device__ inline void atomicMaxF(float* addr, float val){
  int* ia=(int*)addr;
  int old=*ia;
  while (__int_as_float(old) < val){
    int assumed=old;
    old = atomicCAS(ia, assumed, __float_as_int(val));
    if (old == assumed) break;
  }
}

// ---------------- x init: l=0 <- species embed ----------------
__global__ __launch_bounds__(256) void init_x_kernel(const float* __restrict__ spe,
    const int* __restrict__ nsp, float* __restrict__ x, int N){
  int idx = blockIdx.x*256+threadIdx.x;
  if (idx >= N*1600) return;
  int n = idx/1600, lc = idx%1600, l = lc>>6, c = lc&63;
  x[idx] = (l==0) ? spe[nsp[n]*64+c] : 0.0f;
}

// ---------------- shared: build ee rows for 4 edges in LDS ----------------
__device__ inline void build_ee4(int e0, int E, int tid,
    const float* __restrict__ ev, const float* __restrict__ ese,
    const int* __restrict__ snd, const int* __restrict__ rcv, const int* __restrict__ nsp,
    float (*s_ee)[DIN], float* s_d, int* s_ss, int* s_rs){
  if (tid < 4){
    int e = e0 + tid;
    if (e < E){
      float vx=ev[3*e], vy=ev[3*e+1], vz=ev[3*e+2];
      s_d[tid] = sqrtf(vx*vx+vy*vy+vz*vz+1e-12f);
      s_ss[tid] = nsp[snd[e]];
      s_rs[tid] = nsp[rcv[e]];
    } else { s_d[tid]=0.0f; s_ss[tid]=0; s_rs[tid]=0; }
  }
  __syncthreads();
  const float step = 5.0f/599.0f;
  const float inv_std = 1.0f/(2.0f*step);
  for (int j=tid; j<4*DIN; j+=256){
    int le=j/DIN, jj=j%DIN;
    float v;
    if (jj < NRBF){ float t=(s_d[le]-jj*step)*inv_std; v=__expf(-0.5f*t*t); }
    else if (jj < NRBF+64) v = ese[s_ss[le]*128 + (jj-NRBF)];
    else v = ese[s_rs[le]*128 + 64 + (jj-NRBF-64)];
    s_ee[le][jj]=v;
  }
  __syncthreads();
}

// ---------------- edge degree embedding: MLP + rotate + scatter ----------------
__global__ __launch_bounds__(256) void deg_kernel(const float* __restrict__ ev,
    const float* __restrict__ ese, const int* __restrict__ nsp,
    const float* __restrict__ W1, const float* __restrict__ b1,
    const float* __restrict__ W2, const float* __restrict__ b2,
    const float* __restrict__ winv, const int* __restrict__ snd, const int* __restrict__ rcv,
    float* __restrict__ x, int E){
  int e0 = blockIdx.x*4, tid = threadIdx.x;
  __shared__ float s_ee[4][DIN];
  __shared__ float s_h1[4][128];
  __shared__ float s_h2[4][1216];
  __shared__ float s_part[256][4];
  __shared__ float s_d[4]; __shared__ int s_ss[4]; __shared__ int s_rs[4];
  int ne = E - e0; if (ne > 4) ne = 4;
  build_ee4(e0, E, tid, ev, ese, snd, rcv, nsp, s_ee, s_d, s_ss, s_rs);
  {
    int o=tid&127, half=tid>>7, i0=half*364;
    float a0=0,a1=0,a2=0,a3=0;
    for (int i=i0;i<i0+364;i++){
      float w=W1[i*128+o];
      a0+=s_ee[0][i]*w; a1+=s_ee[1][i]*w; a2+=s_ee[2][i]*w; a3+=s_ee[3][i]*w;
    }
    s_part[tid][0]=a0; s_part[tid][1]=a1; s_part[tid][2]=a2; s_part[tid][3]=a3;
  }
  __syncthreads();
  if (tid<128){
    float bb=b1[tid];
    #pragma unroll
    for (int le=0;le<4;le++){
      float a=s_part[tid][le]+s_part[tid+128][le]+bb;
      s_h1[le][tid]=silu_f(a);
    }
  }
  __syncthreads();
  for (int m=tid;m<1216;m+=256){
    float bb=b2[m];
    float a0=bb,a1=bb,a2=bb,a3=bb;
    for (int o=0;o<128;o++){
      float w=W2[o*1216+m];
      a0+=s_h1[0][o]*w; a1+=s_h1[1][o]*w; a2+=s_h1[2][o]*w; a3+=s_h1[3][o]*w;
    }
    s_h2[0][m]=a0; s_h2[1][m]=a1; s_h2[2][m]=a2; s_h2[3][m]=a3;
  }
  __syncthreads();
  for (int le=0;le<ne;le++){
    const float* wi = winv + (size_t)(e0+le)*475;
    int r = rcv[e0+le];
    for (int j=tid;j<1600;j+=256){
      int l=j>>6, c=j&63;
      float acc=0;
      #pragma unroll
      for (int m=0;m<19;m++) acc += wi[l*19+m]*s_h2[le][m*64+c];
      atomicAdd(&x[(size_t)r*1600+j], acc*0.05f);
    }
  }
}

// ---------------- per-degree RMS norm ----------------
__global__ __launch_bounds__(256) void rmsnorm_kernel(const float* __restrict__ x,
    const float* __restrict__ w, float* __restrict__ xn, int N){
  int n = blockIdx.x, tid = threadIdx.x;
  __shared__ float s_x[1600];
  __shared__ float s_part[256];
  __shared__ float s_ms[64];
  const float* xr = x + (size_t)n*1600;
  for (int j=tid;j<1600;j+=256) s_x[j]=xr[j];
  __syncthreads();
  {
    int c = tid&63, seg = tid>>6;
    float acc=0;
    for (int l=seg;l<25;l+=4){ float v=s_x[l*64+c]; acc+=v*v; }
    s_part[tid]=acc;
  }
  __syncthreads();
  if (tid<64){
    float m=(s_part[tid]+s_part[tid+64]+s_part[tid+128]+s_part[tid+192])*(1.0f/25.0f);
    s_ms[tid]=rsqrtf(m+1e-6f);
  }
  __syncthreads();
  float* xo = xn + (size_t)n*1600;
  for (int j=tid;j<1600;j+=256){
    int l=j>>6, c=j&63;
    xo[j]=s_x[j]*s_ms[c]*w[d_loc[l]*64+c];
  }
}

__global__ __launch_bounds__(256) void init_mxden_kernel(float* mx, float* den, int N){
  int idx = blockIdx.x*256+threadIdx.x;
  if (idx < N*8){ mx[idx]=-3.0e38f; den[idx]=0.0f; }
}

// ---------------- radial MLP (per layer) ----------------
__global__ __launch_bounds__(256) void rad_kernel(const float* __restrict__ ev,
    const float* __restrict__ ese, const int* __restrict__ nsp,
    const float* __restrict__ W1, const float* __restrict__ b1,
    const float* __restrict__ W2, const float* __restrict__ b2,
    const int* __restrict__ snd, const int* __restrict__ rcv,
    float* __restrict__ radb, int E){
  int e0 = blockIdx.x*4, tid = threadIdx.x;
  __shared__ float s_ee[4][DIN];
  __shared__ float s_h1[4][128];
  __shared__ float s_part[256][4];
  __shared__ float s_d[4]; __shared__ int s_ss[4]; __shared__ int s_rs[4];
  int ne = E - e0; if (ne > 4) ne = 4;
  build_ee4(e0, E, tid, ev, ese, snd, rcv, nsp, s_ee, s_d, s_ss, s_rs);
  {
    int o=tid&127, half=tid>>7, i0=half*364;
    float a0=0,a1=0,a2=0,a3=0;
    for (int i=i0;i<i0+364;i++){
      float w=W1[i*128+o];
      a0+=s_ee[0][i]*w; a1+=s_ee[1][i]*w; a2+=s_ee[2][i]*w; a3+=s_ee[3][i]*w;
    }
    s_part[tid][0]=a0; s_part[tid][1]=a1; s_part[tid][2]=a2; s_part[tid][3]=a3;
  }
  __syncthreads();
  if (tid<128){
    float bb=b1[tid];
    #pragma unroll
    for (int le=0;le<4;le++){
      float a=s_part[tid][le]+s_part[tid+128][le]+bb;
      s_h1[le][tid]=silu_f(a);
    }
  }
  __syncthreads();
  for (int m=tid;m<384;m+=256){
    float bb=b2[m];
    float a0=bb,a1=bb,a2=bb,a3=bb;
    for (int o=0;o<128;o++){
      float w=W2[o*384+m];
      a0+=s_h1[0][o]*w; a1+=s_h1[1][o]*w; a2+=s_h1[2][o]*w; a3+=s_h1[3][o]*w;
    }
    if (0<ne) radb[(size_t)(e0+0)*384+m]=a0;
    if (1<ne) radb[(size_t)(e0+1)*384+m]=a1;
    if (2<ne) radb[(size_t)(e0+2)*384+m]=a2;
    if (3<ne) radb[(size_t)(e0+3)*384+m]=a3;
  }
}

// ---------------- pass 1: m=0 path -> alpha logits ----------------
__global__ __launch_bounds__(256) void logits_kernel(const float* __restrict__ xn,
    const float* __restrict__ wig, const float* __restrict__ radb,
    const float* __restrict__ so2W, const float* __restrict__ alphaW, const float* __restrict__ alphaV,
    const int* __restrict__ snd, const int* __restrict__ rcv,
    float* __restrict__ logits, float* __restrict__ mx, int E){
  int e = blockIdx.x, tid = threadIdx.x;
  __shared__ float s_cat[3200];
  __shared__ float s_wig0[25];
  __shared__ float s_msg0[128];
  __shared__ float s_sh0[64];
  __shared__ float s_a[256];
  int s = snd[e], r = rcv[e];
  const float* xs = xn + (size_t)s*1600;
  const float* xr = xn + (size_t)r*1600;
  for (int j=tid;j<1600;j+=256){ int l=j>>6, c=j&63; s_cat[l*128+c]=xs[j]; s_cat[l*128+64+c]=xr[j]; }
  if (tid<25) s_wig0[tid]=wig[(size_t)e*475+tid];
  __syncthreads();
  if (tid<128){
    float acc=0;
    #pragma unroll
    for (int l=0;l<25;l++) acc += s_wig0[l]*s_cat[l*128+tid];
    s_msg0[tid]=acc*radb[(size_t)e*384+tid];
  }
  __syncthreads();
  if (tid<64){
    float acc=0;
    #pragma unroll
    for (int k=0;k<128;k++) acc += s_msg0[k]*so2W[k*64+tid];
    s_sh0[tid]=silu_f(acc);
  }
  __syncthreads();
  {
    float acc=0;
    #pragma unroll
    for (int o=0;o<64;o++) acc += s_sh0[o]*alphaW[o*256+tid];
    s_a[tid]=silu_f(acc)*alphaV[tid];
  }
  __syncthreads();
  if (tid<8){
    float lg=0;
    #pragma unroll
    for (int q=0;q<32;q++) lg += s_a[tid*32+q];
    logits[(size_t)e*8+tid]=lg;
    atomicMaxF(&mx[r*8+tid], lg);
  }
}

// ---------------- softmax denominators ----------------
__global__ __launch_bounds__(256) void den_kernel(const float* __restrict__ logits,
    const float* __restrict__ mx, const int* __restrict__ rcv,
    float* __restrict__ den, int E){
  int idx = blockIdx.x*256+threadIdx.x;
  if (idx >= E*8) return;
  int e = idx>>3, hd = idx&7, r = rcv[e];
  atomicAdd(&den[r*8+hd], __expf(logits[idx]-mx[r*8+hd]));
}

// ---------------- pass 2: full SO2 conv + value/proj + rotate back + scatter ----------------
__global__ __launch_bounds__(256) void attn_kernel(const float* __restrict__ xn,
    const float* __restrict__ wig, const float* __restrict__ winv, const float* __restrict__ radb,
    const float* __restrict__ so2W, const float* __restrict__ valW, const float* __restrict__ projW,
    const float* __restrict__ logits, const float* __restrict__ mx, const float* __restrict__ den,
    const int* __restrict__ snd, const int* __restrict__ rcv,
    float* __restrict__ x, int E){
  int e = blockIdx.x, tid = threadIdx.x;
  __shared__ float s_w[8192];     // union: node-cat staging, then weight tiles
  __shared__ float s_wig[475];
  __shared__ float s_winv[475];
  __shared__ float s_rad[384];
  __shared__ float s_msg[2432];   // 19*128
  __shared__ float s_h[1216];     // 19*64
  __shared__ float s_v[1024];     // per-group <=8*128
  __shared__ float s_oe[1216];
  __shared__ float s_attn[8];
  int s = snd[e], r = rcv[e];
  const float* xs = xn + (size_t)s*1600;
  const float* xr = xn + (size_t)r*1600;
  for (int j=tid;j<1600;j+=256){ int l=j>>6, c=j&63; s_w[l*128+c]=xs[j]; s_w[l*128+64+c]=xr[j]; }
  for (int j=tid;j<475;j+=256){ s_wig[j]=wig[(size_t)e*475+j]; s_winv[j]=winv[(size_t)e*475+j]; }
  for (int j=tid;j<384;j+=256) s_rad[j]=radb[(size_t)e*384+j];
  if (tid<8) s_attn[tid]=__expf(logits[(size_t)e*8+tid]-mx[r*8+tid])/(den[r*8+tid]+1e-12f);
  __syncthreads();
  for (int j=tid;j<2432;j+=256){
    int m=j>>7, k=j&127;
    float acc=0;
    #pragma unroll
    for (int l=0;l<25;l++) acc += s_wig[m*25+l]*s_w[l*128+k];
    s_msg[j]=acc*s_rad[d_mg[m]*128+k];
  }
  __syncthreads();
  for (int g=0; g<3; ++g){
    int cnt=d_gcnt[g];
    { // SO2 conv weights
      const float4* src=(const float4*)(so2W + g*8192);
      float4* dst=(float4*)s_w;
      for (int j=tid;j<2048;j+=256) dst[j]=src[j];
    }
    __syncthreads();
    for (int j=tid;j<cnt*64;j+=256){
      int mi=j>>6, o=j&63, m=d_gm[g][mi];
      float acc=0;
      #pragma unroll
      for (int k=0;k<128;k++) acc += s_msg[m*128+k]*s_w[k*64+o];
      s_h[m*64+o]=acc;
    }
    __syncthreads();
    { // value weights
      const float4* src=(const float4*)(valW + g*8192);
      float4* dst=(float4*)s_w;
      for (int j=tid;j<2048;j+=256) dst[j]=src[j];
    }
    __syncthreads();
    for (int j=tid;j<cnt*128;j+=256){
      int mi=j>>7, jj=j&127, m=d_gm[g][mi];
      float acc=0;
      #pragma unroll
      for (int o=0;o<64;o++) acc += s_h[m*64+o]*s_w[o*128+jj];
      s_v[mi*128+jj]=acc*s_attn[jj>>4];
    }
    __syncthreads();
    { // proj weights
      const float4* src=(const float4*)(projW + g*8192);
      float4* dst=(float4*)s_w;
      for (int j=tid;j<2048;j+=256) dst[j]=src[j];
    }
    __syncthreads();
    for (int j=tid;j<cnt*64;j+=256){
      int mi=j>>6, c=j&63, m=d_gm[g][mi];
      float acc=0;
      #pragma unroll
      for (int v=0;v<128;v++) acc += s_v[mi*128+v]*s_w[v*64+c];
      s_oe[m*64+c]=acc;
    }
    __syncthreads();
  }
  for (int j=tid;j<1600;j+=256){
    int l=j>>6, c=j&63;
    float acc=0;
    #pragma unroll
    for (int m=0;m<19;m++) acc += s_winv[l*19+m]*s_oe[m*64+c];
    atomicAdd(&x[(size_t)r*1600+j], acc);
  }
}

// ---------------- S2 grid FFN (per node, fused to_grid->MLP->from_grid) ----------------
__global__ __launch_bounds__(256) void grid_ffn_kernel(const float* __restrict__ xn,
    const float* __restrict__ tg, const float* __restrict__ fg,
    const float* __restrict__ W1, const float* __restrict__ b1, const float* __restrict__ W2,
    float* __restrict__ x, int N){
  int n = blockIdx.x, tid = threadIdx.x;
  __shared__ float s_xn[1600];
  __shared__ float s_W2[8192];
  __shared__ float s_b1[128];
  __shared__ float s_g[4][64];
  __shared__ float s_hid[4][128];
  __shared__ float s_o[4][64];
  const float* xr = xn + (size_t)n*1600;
  for (int j=tid;j<1600;j+=256) s_xn[j]=xr[j];
  {
    const float4* src=(const float4*)W2;
    float4* dst=(float4*)s_W2;
    for (int j=tid;j<2048;j+=256) dst[j]=src[j];
  }
  if (tid<128) s_b1[tid]=b1[tid];
  float accv[7];
  #pragma unroll
  for (int t=0;t<7;t++) accv[t]=0.0f;
  __syncthreads();
  for (int gp=0; gp<GPTS; gp+=4){
    int gpl=tid>>6, c=tid&63;
    {
      float a=0;
      #pragma unroll
      for (int l=0;l<25;l++) a += tg[(gp+gpl)*25+l]*s_xn[l*64+c];
      s_g[gpl][c]=a;
    }
    __syncthreads();
    {
      int hh=tid&127, gh=tid>>7;
      #pragma unroll
      for (int q=0;q<2;q++){
        int gg=gh+2*q;
        float h=s_b1[hh];
        #pragma unroll
        for (int cc=0;cc<64;cc++) h += s_g[gg][cc]*W1[cc*128+hh];
        s_hid[gg][hh]=silu_f(h);
      }
    }
    __syncthreads();
    {
      float o=0;
      #pragma unroll
      for (int hh=0;hh<128;hh++) o += s_hid[gpl][hh]*s_W2[hh*64+c];
      s_o[gpl][c]=o;
    }
    __syncthreads();
    {
      int t=0;
      for (int idx=tid; idx<1600; idx+=256, t++){
        int l=idx>>6, cc=idx&63;
        float s=0;
        #pragma unroll
        for (int g2=0; g2<4; g2++) s += fg[l*288+gp+g2]*s_o[g2][cc];
        accv[t]+=s;
      }
    }
    __syncthreads();
  }
  {
    int t=0;
    for (int idx=tid; idx<1600; idx+=256, t++) x[(size_t)n*1600+idx] += accv[t];
  }
}

// ---------------- final energy head ----------------
__global__ __launch_bounds__(256) void energy_kernel(const float* __restrict__ xn,
    const float* __restrict__ tg, const float* __restrict__ fg,
    const float* __restrict__ W1, const float* __restrict__ b1,
    const float* __restrict__ W2, const float* __restrict__ b2,
    float* __restrict__ out, int N){
  int n = blockIdx.x, tid = threadIdx.x;
  __shared__ float s_xn[1600];
  __shared__ float s_W1[8192];
  __shared__ float s_b1[128];
  __shared__ float s_w2[128];
  __shared__ float s_g[4][64];
  __shared__ float s_hid[4][128];
  __shared__ float s_red[4][64];
  const float* xr = xn + (size_t)n*1600;
  for (int j=tid;j<1600;j+=256) s_xn[j]=xr[j];
  {
    const float4* src=(const float4*)W1;
    float4* dst=(float4*)s_W1;
    for (int j=tid;j<2048;j+=256) dst[j]=src[j];
  }
  if (tid<128){ s_b1[tid]=b1[tid]; s_w2[tid]=W2[tid]; }
  float b2v = b2[0];
  float priv = 0.0f;
  __syncthreads();
  for (int gp=0; gp<GPTS; gp+=4){
    int gpl=tid>>6, c=tid&63;
    {
      float a=0;
      #pragma unroll
      for (int l=0;l<25;l++) a += tg[(gp+gpl)*25+l]*s_xn[l*64+c];
      s_g[gpl][c]=a;
    }
    __syncthreads();
    {
      int hh=tid&127, gh=tid>>7;
      #pragma unroll
      for (int q=0;q<2;q++){
        int gg=gh+2*q;
        float h=s_b1[hh];
        #pragma unroll
        for (int cc=0;cc<64;cc++) h += s_g[gg][cc]*s_W1[cc*128+hh];
        s_hid[gg][hh]=silu_f(h);
      }
    }
    __syncthreads();
    {
      float part = s_hid[gpl][c]*s_w2[c] + s_hid[gpl][c+64]*s_w2[c+64];
      s_red[gpl][c]=part;
    }
    __syncthreads();
    if (tid<4){
      float sum=0;
      #pragma unroll
      for (int q=0;q<64;q++) sum += s_red[tid][q];
      priv += fg[gp+tid]*(sum+b2v);
    }
    __syncthreads();
  }
  if (tid<4) s_red[0][tid]=priv;
  __syncthreads();
  if (tid==0) out[n]=(s_red[0][0]+s_red[0][1]+s_red[0][2]+s_red[0][3])*(1.0f/2000.0f);
}

extern "C" void kernel_launch(void* const* d_in, const int* in_sizes, int n_in,
                              void* d_out, int out_size, void* d_ws, size_t ws_size,
                              hipStream_t stream){
  (void)n_in; (void)out_size; (void)ws_size;
  const float* ev   = (const float*)d_in[0];
  const float* wig  = (const float*)d_in[1];
  const float* winv = (const float*)d_in[2];
  const float* spe  = (const float*)d_in[3];
  const float* ese  = (const float*)d_in[4];
  const float* degW1= (const float*)d_in[5];
  const float* degb1= (const float*)d_in[6];
  const float* degW2= (const float*)d_in[7];
  const float* degb2= (const float*)d_in[8];
  const float* n1w  = (const float*)d_in[9];
  const float* radW1= (const float*)d_in[10];
  const float* radb1= (const float*)d_in[11];
  const float* radW2= (const float*)d_in[12];
  const float* radb2= (const float*)d_in[13];
  const float* so2W = (const float*)d_in[14];
  const float* aW   = (const float*)d_in[15];
  const float* aV   = (const float*)d_in[16];
  const float* vW   = (const float*)d_in[17];
  const float* pW   = (const float*)d_in[18];
  const float* n2w  = (const float*)d_in[19];
  const float* fW1  = (const float*)d_in[20];
  const float* fb1  = (const float*)d_in[21];
  const float* fW2  = (const float*)d_in[22];
  const float* tg   = (const float*)d_in[23];
  const float* fg   = (const float*)d_in[24];
  const float* fnw  = (const float*)d_in[25];
  const float* enW1 = (const float*)d_in[26];
  const float* enb1 = (const float*)d_in[27];
  const float* enW2 = (const float*)d_in[28];
  const float* enb2 = (const float*)d_in[29];
  const int* nsp = (const int*)d_in[30];
  const int* snd = (const int*)d_in[31];
  const int* rcv = (const int*)d_in[32];
  int N = in_sizes[30];
  int E = in_sizes[31];
  float* out = (float*)d_out;

  float* ws = (float*)d_ws;
  size_t off = 0;
  float* radbuf = ws + off; off += (size_t)E*384;
  float* logits = ws + off; off += (size_t)E*8;
  float* mx     = ws + off; off += (size_t)N*8;
  float* den    = ws + off; off += (size_t)N*8;
  float* x      = ws + off; off += (size_t)N*1600;
  float* xn     = ws + off; off += (size_t)N*1600;
  // total ~22.1M floats ~= 88.5 MB

  init_x_kernel<<<(N*1600+255)/256, 256, 0, stream>>>(spe, nsp, x, N);
  deg_kernel<<<(E+3)/4, 256, 0, stream>>>(ev, ese, nsp, degW1, degb1, degW2, degb2,
                                          winv, snd, rcv, x, E);

  for (int i=0;i<2;i++){
    rmsnorm_kernel<<<N, 256, 0, stream>>>(x, n1w + (size_t)i*320, xn, N);
    init_mxden_kernel<<<(N*8+255)/256, 256, 0, stream>>>(mx, den, N);
    rad_kernel<<<(E+3)/4, 256, 0, stream>>>(ev, ese, nsp, radW1 + (size_t)i*DIN*128, radb1 + (size_t)i*128,
                                            radW2 + (size_t)i*128*384, radb2 + (size_t)i*384,
                                            snd, rcv, radbuf, E);
    logits_kernel<<<E, 256, 0, stream>>>(xn, wig, radbuf, so2W + (size_t)i*3*8192,
                                         aW + (size_t)i*64*256, aV + (size_t)i*256,
                                         snd, rcv, logits, mx, E);
    den_kernel<<<(E*8+255)/256, 256, 0, stream>>>(logits, mx, rcv, den, E);
    attn_kernel<<<E, 256, 0, stream>>>(xn, wig, winv, radbuf, so2W + (size_t)i*3*8192,
                                       vW + (size_t)i*3*8192, pW + (size_t)i*3*8192,
                                       logits, mx, den, snd, rcv, x, E);
    rmsnorm_kernel<<<N, 256, 0, stream>>>(x, n2w + (size_t)i*320, xn, N);
    grid_ffn_kernel<<<N, 256, 0, stream>>>(xn, tg, fg, fW1 + (size_t)i*8192, fb1 + (size_t)i*128,
                                           fW2 + (size_t)i*8192, x, N);
  }
  rmsnorm_kernel<<<N, 256, 0, stream>>>(x, fnw, xn, N);
  energy_kernel<<<N, 256, 0, stream>>>(xn, tg, fg, enW1, enb1, enW2, enb2, out, N);
}

// Round 3
// 9238.821 us; speedup vs baseline: 1.7619x; 1.7619x over previous
//
#include <hip/hip_runtime.h>
#include <hip/hip_bf16.h>
#include <math.h>

// EquiformerV2 block, fp32. Round 2: attn_kernel register-tiled, weights via L2.
// E=40000 edges, N=2000 nodes, C=64, L2=25, M2=19, NL=2.

#define NRBF 600
#define DIN 728
#define GPTS 288

__constant__ int d_mg[19] = {0,1,0,1,2,1,0,1,2,2,1,0,1,2,2,1,0,1,2};
__constant__ int d_loc[25] = {0,1,1,1,2,2,2,2,2,3,3,3,3,3,3,3,4,4,4,4,4,4,4,4,4};

__device__ inline float silu_f(float v){ return v/(1.0f+__expf(-v)); }

__device__ inline void atomicMaxF(float* addr, float val){
  int* ia=(int*)addr;
  int old=*ia;
  while (__int_as_float(old) < val){
    int assumed=old;
    old = atomicCAS(ia, assumed, __float_as_int(val));
    if (old == assumed) break;
  }
}

// ---------------- x init ----------------
__global__ __launch_bounds__(256) void init_x_kernel(const float* __restrict__ spe,
    const int* __restrict__ nsp, float* __restrict__ x, int N){
  int idx = blockIdx.x*256+threadIdx.x;
  if (idx >= N*1600) return;
  int n = idx/1600, lc = idx%1600, l = lc>>6, c = lc&63;
  x[idx] = (l==0) ? spe[nsp[n]*64+c] : 0.0f;
}

// ---------------- build ee rows for 4 edges in LDS ----------------
__device__ inline void build_ee4(int e0, int E, int tid,
    const float* __restrict__ ev, const float* __restrict__ ese,
    const int* __restrict__ snd, const int* __restrict__ rcv, const int* __restrict__ nsp,
    float (*s_ee)[DIN], float* s_d, int* s_ss, int* s_rs){
  if (tid < 4){
    int e = e0 + tid;
    if (e < E){
      float vx=ev[3*e], vy=ev[3*e+1], vz=ev[3*e+2];
      s_d[tid] = sqrtf(vx*vx+vy*vy+vz*vz+1e-12f);
      s_ss[tid] = nsp[snd[e]];
      s_rs[tid] = nsp[rcv[e]];
    } else { s_d[tid]=0.0f; s_ss[tid]=0; s_rs[tid]=0; }
  }
  __syncthreads();
  const float step = 5.0f/599.0f;
  const float inv_std = 1.0f/(2.0f*step);
  for (int j=tid; j<4*DIN; j+=256){
    int le=j/DIN, jj=j%DIN;
    float v;
    if (jj < NRBF){ float t=(s_d[le]-jj*step)*inv_std; v=__expf(-0.5f*t*t); }
    else if (jj < NRBF+64) v = ese[s_ss[le]*128 + (jj-NRBF)];
    else v = ese[s_rs[le]*128 + 64 + (jj-NRBF-64)];
    s_ee[le][jj]=v;
  }
  __syncthreads();
}

// ---------------- edge degree embedding ----------------
__global__ __launch_bounds__(256) void deg_kernel(const float* __restrict__ ev,
    const float* __restrict__ ese, const int* __restrict__ nsp,
    const float* __restrict__ W1, const float* __restrict__ b1,
    const float* __restrict__ W2, const float* __restrict__ b2,
    const float* __restrict__ winv, const int* __restrict__ snd, const int* __restrict__ rcv,
    float* __restrict__ x, int E){
  int e0 = blockIdx.x*4, tid = threadIdx.x;
  __shared__ float s_ee[4][DIN];
  __shared__ float s_h1[4][128];
  __shared__ float s_h2[4][1216];
  __shared__ float s_part[256][4];
  __shared__ float s_d[4]; __shared__ int s_ss[4]; __shared__ int s_rs[4];
  int ne = E - e0; if (ne > 4) ne = 4;
  build_ee4(e0, E, tid, ev, ese, snd, rcv, nsp, s_ee, s_d, s_ss, s_rs);
  {
    int o=tid&127, half=tid>>7, i0=half*364;
    float a0=0,a1=0,a2=0,a3=0;
    for (int i=i0;i<i0+364;i++){
      float w=W1[i*128+o];
      a0+=s_ee[0][i]*w; a1+=s_ee[1][i]*w; a2+=s_ee[2][i]*w; a3+=s_ee[3][i]*w;
    }
    s_part[tid][0]=a0; s_part[tid][1]=a1; s_part[tid][2]=a2; s_part[tid][3]=a3;
  }
  __syncthreads();
  if (tid<128){
    float bb=b1[tid];
    #pragma unroll
    for (int le=0;le<4;le++){
      float a=s_part[tid][le]+s_part[tid+128][le]+bb;
      s_h1[le][tid]=silu_f(a);
    }
  }
  __syncthreads();
  for (int m=tid;m<1216;m+=256){
    float bb=b2[m];
    float a0=bb,a1=bb,a2=bb,a3=bb;
    for (int o=0;o<128;o++){
      float w=W2[o*1216+m];
      a0+=s_h1[0][o]*w; a1+=s_h1[1][o]*w; a2+=s_h1[2][o]*w; a3+=s_h1[3][o]*w;
    }
    s_h2[0][m]=a0; s_h2[1][m]=a1; s_h2[2][m]=a2; s_h2[3][m]=a3;
  }
  __syncthreads();
  for (int le=0;le<ne;le++){
    const float* wi = winv + (size_t)(e0+le)*475;
    int r = rcv[e0+le];
    for (int j=tid;j<1600;j+=256){
      int l=j>>6, c=j&63;
      float acc=0;
      #pragma unroll
      for (int m=0;m<19;m++) acc += wi[l*19+m]*s_h2[le][m*64+c];
      atomicAdd(&x[(size_t)r*1600+j], acc*0.05f);
    }
  }
}

// ---------------- per-degree RMS norm ----------------
__global__ __launch_bounds__(256) void rmsnorm_kernel(const float* __restrict__ x,
    const float* __restrict__ w, float* __restrict__ xn, int N){
  int n = blockIdx.x, tid = threadIdx.x;
  __shared__ float s_x[1600];
  __shared__ float s_part[256];
  __shared__ float s_ms[64];
  const float* xr = x + (size_t)n*1600;
  for (int j=tid;j<1600;j+=256) s_x[j]=xr[j];
  __syncthreads();
  {
    int c = tid&63, seg = tid>>6;
    float acc=0;
    for (int l=seg;l<25;l+=4){ float v=s_x[l*64+c]; acc+=v*v; }
    s_part[tid]=acc;
  }
  __syncthreads();
  if (tid<64){
    float m=(s_part[tid]+s_part[tid+64]+s_part[tid+128]+s_part[tid+192])*(1.0f/25.0f);
    s_ms[tid]=rsqrtf(m+1e-6f);
  }
  __syncthreads();
  float* xo = xn + (size_t)n*1600;
  for (int j=tid;j<1600;j+=256){
    int l=j>>6, c=j&63;
    xo[j]=s_x[j]*s_ms[c]*w[d_loc[l]*64+c];
  }
}

__global__ __launch_bounds__(256) void init_mxden_kernel(float* mx, float* den, int N){
  int idx = blockIdx.x*256+threadIdx.x;
  if (idx < N*8){ mx[idx]=-3.0e38f; den[idx]=0.0f; }
}

// ---------------- radial MLP ----------------
__global__ __launch_bounds__(256) void rad_kernel(const float* __restrict__ ev,
    const float* __restrict__ ese, const int* __restrict__ nsp,
    const float* __restrict__ W1, const float* __restrict__ b1,
    const float* __restrict__ W2, const float* __restrict__ b2,
    const int* __restrict__ snd, const int* __restrict__ rcv,
    float* __restrict__ radb, int E){
  int e0 = blockIdx.x*4, tid = threadIdx.x;
  __shared__ float s_ee[4][DIN];
  __shared__ float s_h1[4][128];
  __shared__ float s_part[256][4];
  __shared__ float s_d[4]; __shared__ int s_ss[4]; __shared__ int s_rs[4];
  int ne = E - e0; if (ne > 4) ne = 4;
  build_ee4(e0, E, tid, ev, ese, snd, rcv, nsp, s_ee, s_d, s_ss, s_rs);
  {
    int o=tid&127, half=tid>>7, i0=half*364;
    float a0=0,a1=0,a2=0,a3=0;
    for (int i=i0;i<i0+364;i++){
      float w=W1[i*128+o];
      a0+=s_ee[0][i]*w; a1+=s_ee[1][i]*w; a2+=s_ee[2][i]*w; a3+=s_ee[3][i]*w;
    }
    s_part[tid][0]=a0; s_part[tid][1]=a1; s_part[tid][2]=a2; s_part[tid][3]=a3;
  }
  __syncthreads();
  if (tid<128){
    float bb=b1[tid];
    #pragma unroll
    for (int le=0;le<4;le++){
      float a=s_part[tid][le]+s_part[tid+128][le]+bb;
      s_h1[le][tid]=silu_f(a);
    }
  }
  __syncthreads();
  for (int m=tid;m<384;m+=256){
    float bb=b2[m];
    float a0=bb,a1=bb,a2=bb,a3=bb;
    for (int o=0;o<128;o++){
      float w=W2[o*384+m];
      a0+=s_h1[0][o]*w; a1+=s_h1[1][o]*w; a2+=s_h1[2][o]*w; a3+=s_h1[3][o]*w;
    }
    if (0<ne) radb[(size_t)(e0+0)*384+m]=a0;
    if (1<ne) radb[(size_t)(e0+1)*384+m]=a1;
    if (2<ne) radb[(size_t)(e0+2)*384+m]=a2;
    if (3<ne) radb[(size_t)(e0+3)*384+m]=a3;
  }
}

// ---------------- pass 1: m=0 path -> alpha logits ----------------
__global__ __launch_bounds__(256) void logits_kernel(const float* __restrict__ xn,
    const float* __restrict__ wig, const float* __restrict__ radb,
    const float* __restrict__ so2W, const float* __restrict__ alphaW, const float* __restrict__ alphaV,
    const int* __restrict__ snd, const int* __restrict__ rcv,
    float* __restrict__ logits, float* __restrict__ mx, int E){
  int e = blockIdx.x, tid = threadIdx.x;
  __shared__ float s_cat[3200];
  __shared__ float s_wig0[25];
  __shared__ float s_msg0[128];
  __shared__ float s_sh0[64];
  __shared__ float s_a[256];
  int s = snd[e], r = rcv[e];
  const float4* xs4 = (const float4*)(xn + (size_t)s*1600);
  const float4* xr4 = (const float4*)(xn + (size_t)r*1600);
  float4* cat4 = (float4*)s_cat;
  for (int j=tid;j<400;j+=256){
    int l=j>>4, c4=j&15;
    cat4[l*32+c4]    = xs4[j];
    cat4[l*32+16+c4] = xr4[j];
  }
  if (tid<25) s_wig0[tid]=wig[(size_t)e*475+tid];
  __syncthreads();
  if (tid<128){
    float acc=0;
    #pragma unroll
    for (int l=0;l<25;l++) acc += s_wig0[l]*s_cat[l*128+tid];
    s_msg0[tid]=acc*radb[(size_t)e*384+tid];
  }
  __syncthreads();
  if (tid<64){
    float acc=0;
    #pragma unroll
    for (int k=0;k<128;k++) acc += s_msg0[k]*so2W[k*64+tid];
    s_sh0[tid]=silu_f(acc);
  }
  __syncthreads();
  {
    float acc=0;
    #pragma unroll
    for (int o=0;o<64;o++) acc += s_sh0[o]*alphaW[o*256+tid];
    s_a[tid]=silu_f(acc)*alphaV[tid];
  }
  __syncthreads();
  if (tid<8){
    float lg=0;
    #pragma unroll
    for (int q=0;q<32;q++) lg += s_a[tid*32+q];
    logits[(size_t)e*8+tid]=lg;
    atomicMaxF(&mx[r*8+tid], lg);
  }
}

// ---------------- softmax denominators ----------------
__global__ __launch_bounds__(256) void den_kernel(const float* __restrict__ logits,
    const float* __restrict__ mx, const int* __restrict__ rcv,
    float* __restrict__ den, int E){
  int idx = blockIdx.x*256+threadIdx.x;
  if (idx >= E*8) return;
  int e = idx>>3, hd = idx&7, r = rcv[e];
  atomicAdd(&den[r*8+hd], __expf(logits[idx]-mx[r*8+hd]));
}

// ---------------- pass 2: SO2 conv + value/proj + rotate back + scatter ----------------
// Register-tiled float4; weights read straight from L2 (no LDS staging).
__global__ __launch_bounds__(256) void attn_kernel(const float* __restrict__ xn,
    const float* __restrict__ wig, const float* __restrict__ winv, const float* __restrict__ radb,
    const float* __restrict__ so2W, const float* __restrict__ valW, const float* __restrict__ projW,
    const float* __restrict__ logits, const float* __restrict__ mx, const float* __restrict__ den,
    const int* __restrict__ snd, const int* __restrict__ rcv,
    float* __restrict__ x, int E){
  int e = blockIdx.x, tid = threadIdx.x;
  __shared__ float s_uni[3648];   // cat[3200] THEN {v[2432], oe[1216]}
  __shared__ float s_msg[2432];   // 19*128
  __shared__ float s_h[1216];     // 19*64
  __shared__ float s_wig[475];
  __shared__ float s_winv[475];
  __shared__ float s_rad[384];
  __shared__ float s_attn[8];
  float* s_cat = s_uni;
  float* s_v   = s_uni;
  float* s_oe  = s_uni + 2432;
  int s = snd[e], r = rcv[e];
  // ---- stage loads ----
  {
    const float4* xs4=(const float4*)(xn + (size_t)s*1600);
    const float4* xr4=(const float4*)(xn + (size_t)r*1600);
    float4* cat4=(float4*)s_cat;
    for (int j=tid;j<400;j+=256){
      int l=j>>4, c4=j&15;
      cat4[l*32+c4]    = xs4[j];
      cat4[l*32+16+c4] = xr4[j];
    }
  }
  for (int j=tid;j<475;j+=256){ s_wig[j]=wig[(size_t)e*475+j]; s_winv[j]=winv[(size_t)e*475+j]; }
  for (int j=tid;j<96;j+=256) ((float4*)s_rad)[j]=((const float4*)(radb+(size_t)e*384))[j];
  if (tid<8) s_attn[tid]=__expf(logits[(size_t)e*8+tid]-mx[r*8+tid])/(den[r*8+tid]+1e-12f);
  __syncthreads();
  // ---- msg = wigner-rotate(cat) * rad ----  [19][128]
  for (int sI=tid; sI<608; sI+=256){
    int m=sI>>5, k4=sI&31;
    const float* wr = s_wig + m*25;
    const float4* catp=(const float4*)s_cat;
    float4 acc={0,0,0,0};
    #pragma unroll
    for (int l=0;l<25;l++){
      float w=wr[l];
      float4 cv=catp[l*32+k4];
      acc.x+=w*cv.x; acc.y+=w*cv.y; acc.z+=w*cv.z; acc.w+=w*cv.w;
    }
    float4 rv=((const float4*)s_rad)[d_mg[m]*32+k4];
    acc.x*=rv.x; acc.y*=rv.y; acc.z*=rv.z; acc.w*=rv.w;
    ((float4*)s_msg)[m*32+k4]=acc;
  }
  __syncthreads();
  // ---- h[m][o] = msg[m][:] @ so2W[g(m)][:][o] ----  [19][64], K=128
  for (int sI=tid; sI<304; sI+=256){
    int m=sI>>4, o4=sI&15;
    const float4* W=(const float4*)(so2W + d_mg[m]*8192);
    const float4* msgp=(const float4*)s_msg + m*32;
    float4 acc={0,0,0,0};
    #pragma unroll 2
    for (int k4=0;k4<32;k4++){
      float4 mv=msgp[k4];
      float4 w0=W[(k4*4+0)*16+o4];
      float4 w1=W[(k4*4+1)*16+o4];
      float4 w2=W[(k4*4+2)*16+o4];
      float4 w3=W[(k4*4+3)*16+o4];
      acc.x += mv.x*w0.x + mv.y*w1.x + mv.z*w2.x + mv.w*w3.x;
      acc.y += mv.x*w0.y + mv.y*w1.y + mv.z*w2.y + mv.w*w3.y;
      acc.z += mv.x*w0.z + mv.y*w1.z + mv.z*w2.z + mv.w*w3.z;
      acc.w += mv.x*w0.w + mv.y*w1.w + mv.z*w2.w + mv.w*w3.w;
    }
    ((float4*)s_h)[m*16+o4]=acc;
  }
  __syncthreads();
  // ---- v[m][jj] = (h[m][:] @ valW[g(m)][:][jj]) * attn[jj>>4] ----  [19][128], K=64
  for (int sI=tid; sI<608; sI+=256){
    int m=sI>>5, j4=sI&31;
    const float4* V=(const float4*)(valW + d_mg[m]*8192);
    const float4* hp=(const float4*)s_h + m*16;
    float4 acc={0,0,0,0};
    #pragma unroll 2
    for (int o4=0;o4<16;o4++){
      float4 hv=hp[o4];
      float4 w0=V[(o4*4+0)*32+j4];
      float4 w1=V[(o4*4+1)*32+j4];
      float4 w2=V[(o4*4+2)*32+j4];
      float4 w3=V[(o4*4+3)*32+j4];
      acc.x += hv.x*w0.x + hv.y*w1.x + hv.z*w2.x + hv.w*w3.x;
      acc.y += hv.x*w0.y + hv.y*w1.y + hv.z*w2.y + hv.w*w3.y;
      acc.z += hv.x*w0.z + hv.y*w1.z + hv.z*w2.z + hv.w*w3.z;
      acc.w += hv.x*w0.w + hv.y*w1.w + hv.z*w2.w + hv.w*w3.w;
    }
    float a=s_attn[j4>>2];
    acc.x*=a; acc.y*=a; acc.z*=a; acc.w*=a;
    ((float4*)s_v)[m*32+j4]=acc;
  }
  __syncthreads();
  // ---- oe[m][c] = v[m][:] @ projW[g(m)][:][c] ----  [19][64], K=128
  for (int sI=tid; sI<304; sI+=256){
    int m=sI>>4, c4=sI&15;
    const float4* P=(const float4*)(projW + d_mg[m]*8192);
    const float4* vp=(const float4*)s_v + m*32;
    float4 acc={0,0,0,0};
    #pragma unroll 2
    for (int v4=0;v4<32;v4++){
      float4 vv=vp[v4];
      float4 w0=P[(v4*4+0)*16+c4];
      float4 w1=P[(v4*4+1)*16+c4];
      float4 w2=P[(v4*4+2)*16+c4];
      float4 w3=P[(v4*4+3)*16+c4];
      acc.x += vv.x*w0.x + vv.y*w1.x + vv.z*w2.x + vv.w*w3.x;
      acc.y += vv.x*w0.y + vv.y*w1.y + vv.z*w2.y + vv.w*w3.y;
      acc.z += vv.x*w0.z + vv.y*w1.z + vv.z*w2.z + vv.w*w3.z;
      acc.w += vv.x*w0.w + vv.y*w1.w + vv.z*w2.w + vv.w*w3.w;
    }
    ((float4*)s_oe)[m*16+c4]=acc;
  }
  __syncthreads();
  // ---- rotate back (winv) + scatter ----
  for (int sI=tid; sI<400; sI+=256){
    int l=sI>>4, c4=sI&15;
    const float* wr=s_winv + l*19;
    const float4* oep=(const float4*)s_oe;
    float4 acc={0,0,0,0};
    #pragma unroll
    for (int m=0;m<19;m++){
      float w=wr[m];
      float4 ov=oep[m*16+c4];
      acc.x+=w*ov.x; acc.y+=w*ov.y; acc.z+=w*ov.z; acc.w+=w*ov.w;
    }
    float* dst=&x[(size_t)r*1600 + l*64 + c4*4];
    atomicAdd(dst+0,acc.x); atomicAdd(dst+1,acc.y);
    atomicAdd(dst+2,acc.z); atomicAdd(dst+3,acc.w);
  }
}

// ---------------- S2 grid FFN ----------------
__global__ __launch_bounds__(256) void grid_ffn_kernel(const float* __restrict__ xn,
    const float* __restrict__ tg, const float* __restrict__ fg,
    const float* __restrict__ W1, const float* __restrict__ b1, const float* __restrict__ W2,
    float* __restrict__ x, int N){
  int n = blockIdx.x, tid = threadIdx.x;
  __shared__ float s_xn[1600];
  __shared__ float s_W2[8192];
  __shared__ float s_b1[128];
  __shared__ float s_g[4][64];
  __shared__ float s_hid[4][128];
  __shared__ float s_o[4][64];
  const float* xr = xn + (size_t)n*1600;
  for (int j=tid;j<1600;j+=256) s_xn[j]=xr[j];
  {
    const float4* src=(const float4*)W2;
    float4* dst=(float4*)s_W2;
    for (int j=tid;j<2048;j+=256) dst[j]=src[j];
  }
  if (tid<128) s_b1[tid]=b1[tid];
  float accv[7];
  #pragma unroll
  for (int t=0;t<7;t++) accv[t]=0.0f;
  __syncthreads();
  for (int gp=0; gp<GPTS; gp+=4){
    int gpl=tid>>6, c=tid&63;
    {
      float a=0;
      #pragma unroll
      for (int l=0;l<25;l++) a += tg[(gp+gpl)*25+l]*s_xn[l*64+c];
      s_g[gpl][c]=a;
    }
    __syncthreads();
    {
      int hh=tid&127, gh=tid>>7;
      #pragma unroll
      for (int q=0;q<2;q++){
        int gg=gh+2*q;
        float h=s_b1[hh];
        #pragma unroll
        for (int cc=0;cc<64;cc++) h += s_g[gg][cc]*W1[cc*128+hh];
        s_hid[gg][hh]=silu_f(h);
      }
    }
    __syncthreads();
    {
      float o=0;
      #pragma unroll
      for (int hh=0;hh<128;hh++) o += s_hid[gpl][hh]*s_W2[hh*64+c];
      s_o[gpl][c]=o;
    }
    __syncthreads();
    {
      int t=0;
      for (int idx=tid; idx<1600; idx+=256, t++){
        int l=idx>>6, cc=idx&63;
        float s=0;
        #pragma unroll
        for (int g2=0; g2<4; g2++) s += fg[l*288+gp+g2]*s_o[g2][cc];
        accv[t]+=s;
      }
    }
    __syncthreads();
  }
  {
    int t=0;
    for (int idx=tid; idx<1600; idx+=256, t++) x[(size_t)n*1600+idx] += accv[t];
  }
}

// ---------------- final energy head ----------------
__global__ __launch_bounds__(256) void energy_kernel(const float* __restrict__ xn,
    const float* __restrict__ tg, const float* __restrict__ fg,
    const float* __restrict__ W1, const float* __restrict__ b1,
    const float* __restrict__ W2, const float* __restrict__ b2,
    float* __restrict__ out, int N){
  int n = blockIdx.x, tid = threadIdx.x;
  __shared__ float s_xn[1600];
  __shared__ float s_W1[8192];
  __shared__ float s_b1[128];
  __shared__ float s_w2[128];
  __shared__ float s_g[4][64];
  __shared__ float s_hid[4][128];
  __shared__ float s_red[4][64];
  const float* xr = xn + (size_t)n*1600;
  for (int j=tid;j<1600;j+=256) s_xn[j]=xr[j];
  {
    const float4* src=(const float4*)W1;
    float4* dst=(float4*)s_W1;
    for (int j=tid;j<2048;j+=256) dst[j]=src[j];
  }
  if (tid<128){ s_b1[tid]=b1[tid]; s_w2[tid]=W2[tid]; }
  float b2v = b2[0];
  float priv = 0.0f;
  __syncthreads();
  for (int gp=0; gp<GPTS; gp+=4){
    int gpl=tid>>6, c=tid&63;
    {
      float a=0;
      #pragma unroll
      for (int l=0;l<25;l++) a += tg[(gp+gpl)*25+l]*s_xn[l*64+c];
      s_g[gpl][c]=a;
    }
    __syncthreads();
    {
      int hh=tid&127, gh=tid>>7;
      #pragma unroll
      for (int q=0;q<2;q++){
        int gg=gh+2*q;
        float h=s_b1[hh];
        #pragma unroll
        for (int cc=0;cc<64;cc++) h += s_g[gg][cc]*s_W1[cc*128+hh];
        s_hid[gg][hh]=silu_f(h);
      }
    }
    __syncthreads();
    {
      float part = s_hid[gpl][c]*s_w2[c] + s_hid[gpl][c+64]*s_w2[c+64];
      s_red[gpl][c]=part;
    }
    __syncthreads();
    if (tid<4){
      float sum=0;
      #pragma unroll
      for (int q=0;q<64;q++) sum += s_red[tid][q];
      priv += fg[gp+tid]*(sum+b2v);
    }
    __syncthreads();
  }
  if (tid<4) s_red[0][tid]=priv;
  __syncthreads();
  if (tid==0) out[n]=(s_red[0][0]+s_red[0][1]+s_red[0][2]+s_red[0][3])*(1.0f/2000.0f);
}

extern "C" void kernel_launch(void* const* d_in, const int* in_sizes, int n_in,
                              void* d_out, int out_size, void* d_ws, size_t ws_size,
                              hipStream_t stream){
  (void)n_in; (void)out_size; (void)ws_size;
  const float* ev   = (const float*)d_in[0];
  const float* wig  = (const float*)d_in[1];
  const float* winv = (const float*)d_in[2];
  const float* spe  = (const float*)d_in[3];
  const float* ese  = (const float*)d_in[4];
  const float* degW1= (const float*)d_in[5];
  const float* degb1= (const float*)d_in[6];
  const float* degW2= (const float*)d_in[7];
  const float* degb2= (const float*)d_in[8];
  const float* n1w  = (const float*)d_in[9];
  const float* radW1= (const float*)d_in[10];
  const float* radb1= (const float*)d_in[11];
  const float* radW2= (const float*)d_in[12];
  const float* radb2= (const float*)d_in[13];
  const float* so2W = (const float*)d_in[14];
  const float* aW   = (const float*)d_in[15];
  const float* aV   = (const float*)d_in[16];
  const float* vW   = (const float*)d_in[17];
  const float* pW   = (const float*)d_in[18];
  const float* n2w  = (const float*)d_in[19];
  const float* fW1  = (const float*)d_in[20];
  const float* fb1  = (const float*)d_in[21];
  const float* fW2  = (const float*)d_in[22];
  const float* tg   = (const float*)d_in[23];
  const float* fg   = (const float*)d_in[24];
  const float* fnw  = (const float*)d_in[25];
  const float* enW1 = (const float*)d_in[26];
  const float* enb1 = (const float*)d_in[27];
  const float* enW2 = (const float*)d_in[28];
  const float* enb2 = (const float*)d_in[29];
  const int* nsp = (const int*)d_in[30];
  const int* snd = (const int*)d_in[31];
  const int* rcv = (const int*)d_in[32];
  int N = in_sizes[30];
  int E = in_sizes[31];
  float* out = (float*)d_out;

  float* ws = (float*)d_ws;
  size_t off = 0;
  float* radbuf = ws + off; off += (size_t)E*384;
  float* logits = ws + off; off += (size_t)E*8;
  float* mx     = ws + off; off += (size_t)N*8;
  float* den    = ws + off; off += (size_t)N*8;
  float* x      = ws + off; off += (size_t)N*1600;
  float* xn     = ws + off; off += (size_t)N*1600;

  init_x_kernel<<<(N*1600+255)/256, 256, 0, stream>>>(spe, nsp, x, N);
  deg_kernel<<<(E+3)/4, 256, 0, stream>>>(ev, ese, nsp, degW1, degb1, degW2, degb2,
                                          winv, snd, rcv, x, E);

  for (int i=0;i<2;i++){
    rmsnorm_kernel<<<N, 256, 0, stream>>>(x, n1w + (size_t)i*320, xn, N);
    init_mxden_kernel<<<(N*8+255)/256, 256, 0, stream>>>(mx, den, N);
    rad_kernel<<<(E+3)/4, 256, 0, stream>>>(ev, ese, nsp, radW1 + (size_t)i*DIN*128, radb1 + (size_t)i*128,
                                            radW2 + (size_t)i*128*384, radb2 + (size_t)i*384,
                                            snd, rcv, radbuf, E);
    logits_kernel<<<E, 256, 0, stream>>>(xn, wig, radbuf, so2W + (size_t)i*3*8192,
                                         aW + (size_t)i*64*256, aV + (size_t)i*256,
                                         snd, rcv, logits, mx, E);
    den_kernel<<<(E*8+255)/256, 256, 0, stream>>>(logits, mx, rcv, den, E);
    attn_kernel<<<E, 256, 0, stream>>>(xn, wig, winv, radbuf, so2W + (size_t)i*3*8192,
                                       vW + (size_t)i*3*8192, pW + (size_t)i*3*8192,
                                       logits, mx, den, snd, rcv, x, E);
    rmsnorm_kernel<<<N, 256, 0, stream>>>(x, n2w + (size_t)i*320, xn, N);
    grid_ffn_kernel<<<N, 256, 0, stream>>>(xn, tg, fg, fW1 + (size_t)i*8192, fb1 + (size_t)i*128,
                                           fW2 + (size_t)i*8192, x, N);
  }
  rmsnorm_kernel<<<N, 256, 0, stream>>>(x, fnw, xn, N);
  energy_kernel<<<N, 256, 0, stream>>>(xn, tg, fg, enW1, enb1, enW2, enb2, out, N);
}

// Round 4
// 8657.619 us; speedup vs baseline: 1.8802x; 1.0671x over previous
//
#include <hip/hip_runtime.h>
#include <hip/hip_bf16.h>
#include <math.h>

// EquiformerV2 block, fp32. Round 4: CSR gather (no big atomics), row-batched weight reuse.
// E=40000 edges, N=2000 nodes, C=64, L2=25, M2=19, NL=2.

#define NRBF 600
#define DIN 728
#define GPTS 288
#define MAXE 160

__constant__ int d_mg[19] = {0,1,0,1,2,1,0,1,2,2,1,0,1,2,2,1,0,1,2};
__constant__ int d_loc[25] = {0,1,1,1,2,2,2,2,2,3,3,3,3,3,3,3,4,4,4,4,4,4,4,4,4};
// 6 row-batches (<=4 rows, same m-group). Padded with row 0; d_bn = valid rows.
__constant__ int d_b4[6][4] = {{0,2,6,11},{16,0,0,0},{1,3,5,7},{10,12,15,17},{4,8,9,13},{14,18,0,0}};
__constant__ int d_bg[6] = {0,0,1,1,2,2};
__constant__ int d_bn[6] = {4,1,4,4,4,2};

__device__ inline float silu_f(float v){ return v/(1.0f+__expf(-v)); }

__device__ inline void atomicMaxF(float* addr, float val){
  int* ia=(int*)addr;
  int old=*ia;
  while (__int_as_float(old) < val){
    int assumed=old;
    old = atomicCAS(ia, assumed, __float_as_int(val));
    if (old == assumed) break;
  }
}

// ---------------- CSR build ----------------
__global__ __launch_bounds__(256) void zero_cnt_kernel(int* cnt, int N){
  int i = blockIdx.x*256+threadIdx.x;
  if (i<N) cnt[i]=0;
}
__global__ __launch_bounds__(256) void csr_count_kernel(const int* __restrict__ rcv, int* cnt, int E){
  int i = blockIdx.x*256+threadIdx.x;
  if (i<E) atomicAdd(&cnt[rcv[i]],1);
}
__global__ __launch_bounds__(256) void csr_scan_kernel(const int* __restrict__ cnt,
    int* rowptr, int* fill, int N){
  __shared__ int s_part[256];
  int tid=threadIdx.x;
  int chunk=(N+255)/256;      // 8 for N=2000
  int lvals[12];
  int base=tid*chunk;
  int lsum=0;
  for (int i=0;i<chunk && i<12;i++){
    int v=(base+i<N)?cnt[base+i]:0;
    lvals[i]=lsum; lsum+=v;
  }
  s_part[tid]=lsum;
  __syncthreads();
  if (tid==0){
    int run=0;
    for (int t=0;t<256;t++){ int v=s_part[t]; s_part[t]=run; run+=v; }
  }
  __syncthreads();
  int off=s_part[tid];
  for (int i=0;i<chunk && i<12;i++){
    if (base+i<N){ rowptr[base+i]=off+lvals[i]; fill[base+i]=off+lvals[i]; }
  }
  if (tid==255) rowptr[N]=off+lsum;
}
__global__ __launch_bounds__(256) void csr_fill_kernel(const int* __restrict__ rcv,
    int* fill, int* eix, int E){
  int i = blockIdx.x*256+threadIdx.x;
  if (i<E){ int p=atomicAdd(&fill[rcv[i]],1); eix[p]=i; }
}

// ---------------- edge degree embedding, gather form (per node) ----------------
__global__ __launch_bounds__(256) void deg_gather_kernel(const float* __restrict__ ev,
    const float* __restrict__ ese, const int* __restrict__ nsp, const float* __restrict__ spe,
    const float* __restrict__ W1, const float* __restrict__ b1,
    const float* __restrict__ W2, const float* __restrict__ b2,
    const float* __restrict__ winv, const int* __restrict__ snd,
    const int* __restrict__ rowptr, const int* __restrict__ eix,
    float* __restrict__ x, int N){
  int n = blockIdx.x, tid = threadIdx.x;
  __shared__ float s_ee[4][DIN];
  __shared__ float s_h1[4][128];
  __shared__ float s_h2[4][1216];
  __shared__ float s_part[256][4];
  __shared__ float s_acc[1600];
  __shared__ float s_winv[475];
  __shared__ int s_eix[MAXE];
  __shared__ float s_d[4]; __shared__ int s_ss[4]; __shared__ int s_rs[4];
  int row0=rowptr[n];
  int cnt=rowptr[n+1]-row0; if (cnt>MAXE) cnt=MAXE;
  {
    float4 z={0,0,0,0};
    for (int j=tid;j<400;j+=256) ((float4*)s_acc)[j]=z;
    for (int j=tid;j<cnt;j+=256) s_eix[j]=eix[row0+j];
  }
  __syncthreads();
  int nq=(cnt+3)>>2;
  for (int q=0;q<nq;q++){
    int qb=q*4;
    int ne=cnt-qb; if (ne>4) ne=4;
    if (tid<4){
      int le=qb+tid;
      if (le<cnt){
        int e=s_eix[le];
        float vx=ev[3*e], vy=ev[3*e+1], vz=ev[3*e+2];
        s_d[tid]=sqrtf(vx*vx+vy*vy+vz*vz+1e-12f);
        s_ss[tid]=nsp[snd[e]];
        s_rs[tid]=nsp[n];
      } else { s_d[tid]=0.0f; s_ss[tid]=0; s_rs[tid]=0; }
    }
    __syncthreads();
    const float step = 5.0f/599.0f;
    const float inv_std = 1.0f/(2.0f*step);
    for (int j=tid;j<4*DIN;j+=256){
      int le=j/DIN, jj=j%DIN;
      float v;
      if (jj<NRBF){ float t=(s_d[le]-jj*step)*inv_std; v=__expf(-0.5f*t*t); }
      else if (jj<NRBF+64) v=ese[s_ss[le]*128+(jj-NRBF)];
      else v=ese[s_rs[le]*128+64+(jj-NRBF-64)];
      s_ee[le][jj]=v;
    }
    __syncthreads();
    {
      int o=tid&127, half=tid>>7, i0=half*364;
      float a0=0,a1=0,a2=0,a3=0;
      for (int i=i0;i<i0+364;i++){
        float w=W1[i*128+o];
        a0+=s_ee[0][i]*w; a1+=s_ee[1][i]*w; a2+=s_ee[2][i]*w; a3+=s_ee[3][i]*w;
      }
      s_part[tid][0]=a0; s_part[tid][1]=a1; s_part[tid][2]=a2; s_part[tid][3]=a3;
    }
    __syncthreads();
    if (tid<128){
      float bb=b1[tid];
      #pragma unroll
      for (int le=0;le<4;le++){
        float a=s_part[tid][le]+s_part[tid+128][le]+bb;
        s_h1[le][tid]=silu_f(a);
      }
    }
    __syncthreads();
    for (int m=tid;m<1216;m+=256){
      float bb=b2[m];
      float a0=bb,a1=bb,a2=bb,a3=bb;
      for (int o=0;o<128;o++){
        float w=W2[o*1216+m];
        a0+=s_h1[0][o]*w; a1+=s_h1[1][o]*w; a2+=s_h1[2][o]*w; a3+=s_h1[3][o]*w;
      }
      s_h2[0][m]=a0; s_h2[1][m]=a1; s_h2[2][m]=a2; s_h2[3][m]=a3;
    }
    __syncthreads();
    for (int le2=0;le2<ne;le2++){
      int e=s_eix[qb+le2];
      for (int j=tid;j<475;j+=256) s_winv[j]=winv[(size_t)e*475+j];
      __syncthreads();
      const float4* H2=(const float4*)s_h2[le2];
      for (int sI=tid;sI<400;sI+=256){
        int l=sI>>4, c4=sI&15;
        const float* wr=s_winv+l*19;
        float4 acc={0,0,0,0};
        #pragma unroll
        for (int m=0;m<19;m++){
          float w=wr[m];
          float4 hv=H2[m*16+c4];
          acc.x+=w*hv.x; acc.y+=w*hv.y; acc.z+=w*hv.z; acc.w+=w*hv.w;
        }
        float4* A=(float4*)s_acc;
        float4 cur=A[sI];
        cur.x+=acc.x; cur.y+=acc.y; cur.z+=acc.z; cur.w+=acc.w;
        A[sI]=cur;
      }
      __syncthreads();
    }
  }
  int sp=nsp[n];
  for (int j=tid;j<1600;j+=256){
    int l=j>>6, c=j&63;
    float base=(l==0)?spe[sp*64+c]:0.0f;
    x[(size_t)n*1600+j]=base+0.05f*s_acc[j];
  }
}

// ---------------- per-degree RMS norm ----------------
__global__ __launch_bounds__(256) void rmsnorm_kernel(const float* __restrict__ x,
    const float* __restrict__ w, float* __restrict__ xn, int N){
  int n = blockIdx.x, tid = threadIdx.x;
  __shared__ float s_x[1600];
  __shared__ float s_part[256];
  __shared__ float s_ms[64];
  const float* xr = x + (size_t)n*1600;
  for (int j=tid;j<1600;j+=256) s_x[j]=xr[j];
  __syncthreads();
  {
    int c = tid&63, seg = tid>>6;
    float acc=0;
    for (int l=seg;l<25;l+=4){ float v=s_x[l*64+c]; acc+=v*v; }
    s_part[tid]=acc;
  }
  __syncthreads();
  if (tid<64){
    float m=(s_part[tid]+s_part[tid+64]+s_part[tid+128]+s_part[tid+192])*(1.0f/25.0f);
    s_ms[tid]=rsqrtf(m+1e-6f);
  }
  __syncthreads();
  float* xo = xn + (size_t)n*1600;
  for (int j=tid;j<1600;j+=256){
    int l=j>>6, c=j&63;
    xo[j]=s_x[j]*s_ms[c]*w[d_loc[l]*64+c];
  }
}

__global__ __launch_bounds__(256) void init_mxden_kernel(float* mx, float* den, int N){
  int idx = blockIdx.x*256+threadIdx.x;
  if (idx < N*8){ mx[idx]=-3.0e38f; den[idx]=0.0f; }
}

// ---------------- radial MLP (edge-parallel, 4 edges/block) ----------------
__global__ __launch_bounds__(256) void rad_kernel(const float* __restrict__ ev,
    const float* __restrict__ ese, const int* __restrict__ nsp,
    const float* __restrict__ W1, const float* __restrict__ b1,
    const float* __restrict__ W2, const float* __restrict__ b2,
    const int* __restrict__ snd, const int* __restrict__ rcv,
    float* __restrict__ radb, int E){
  int e0 = blockIdx.x*4, tid = threadIdx.x;
  __shared__ float s_ee[4][DIN];
  __shared__ float s_h1[4][128];
  __shared__ float s_part[256][4];
  __shared__ float s_d[4]; __shared__ int s_ss[4]; __shared__ int s_rs[4];
  int ne = E - e0; if (ne > 4) ne = 4;
  if (tid<4){
    int e=e0+tid;
    if (e<E){
      float vx=ev[3*e], vy=ev[3*e+1], vz=ev[3*e+2];
      s_d[tid]=sqrtf(vx*vx+vy*vy+vz*vz+1e-12f);
      s_ss[tid]=nsp[snd[e]]; s_rs[tid]=nsp[rcv[e]];
    } else { s_d[tid]=0.0f; s_ss[tid]=0; s_rs[tid]=0; }
  }
  __syncthreads();
  const float step = 5.0f/599.0f;
  const float inv_std = 1.0f/(2.0f*step);
  for (int j=tid;j<4*DIN;j+=256){
    int le=j/DIN, jj=j%DIN;
    float v;
    if (jj<NRBF){ float t=(s_d[le]-jj*step)*inv_std; v=__expf(-0.5f*t*t); }
    else if (jj<NRBF+64) v=ese[s_ss[le]*128+(jj-NRBF)];
    else v=ese[s_rs[le]*128+64+(jj-NRBF-64)];
    s_ee[le][jj]=v;
  }
  __syncthreads();
  {
    int o=tid&127, half=tid>>7, i0=half*364;
    float a0=0,a1=0,a2=0,a3=0;
    for (int i=i0;i<i0+364;i++){
      float w=W1[i*128+o];
      a0+=s_ee[0][i]*w; a1+=s_ee[1][i]*w; a2+=s_ee[2][i]*w; a3+=s_ee[3][i]*w;
    }
    s_part[tid][0]=a0; s_part[tid][1]=a1; s_part[tid][2]=a2; s_part[tid][3]=a3;
  }
  __syncthreads();
  if (tid<128){
    float bb=b1[tid];
    #pragma unroll
    for (int le=0;le<4;le++){
      float a=s_part[tid][le]+s_part[tid+128][le]+bb;
      s_h1[le][tid]=silu_f(a);
    }
  }
  __syncthreads();
  for (int m=tid;m<384;m+=256){
    float bb=b2[m];
    float a0=bb,a1=bb,a2=bb,a3=bb;
    for (int o=0;o<128;o++){
      float w=W2[o*384+m];
      a0+=s_h1[0][o]*w; a1+=s_h1[1][o]*w; a2+=s_h1[2][o]*w; a3+=s_h1[3][o]*w;
    }
    if (0<ne) radb[(size_t)(e0+0)*384+m]=a0;
    if (1<ne) radb[(size_t)(e0+1)*384+m]=a1;
    if (2<ne) radb[(size_t)(e0+2)*384+m]=a2;
    if (3<ne) radb[(size_t)(e0+3)*384+m]=a3;
  }
}

// ---------------- pass 1: m=0 path -> alpha logits (edge-parallel) ----------------
__global__ __launch_bounds__(256) void logits_kernel(const float* __restrict__ xn,
    const float* __restrict__ wig, const float* __restrict__ radb,
    const float* __restrict__ so2W, const float* __restrict__ alphaW, const float* __restrict__ alphaV,
    const int* __restrict__ snd, const int* __restrict__ rcv,
    float* __restrict__ logits, float* __restrict__ mx, int E){
  int e = blockIdx.x, tid = threadIdx.x;
  __shared__ float s_cat[3200];
  __shared__ float s_wig0[25];
  __shared__ float s_msg0[128];
  __shared__ float s_sh0[64];
  __shared__ float s_a[256];
  int s = snd[e], r = rcv[e];
  const float4* xs4 = (const float4*)(xn + (size_t)s*1600);
  const float4* xr4 = (const float4*)(xn + (size_t)r*1600);
  float4* cat4 = (float4*)s_cat;
  for (int j=tid;j<400;j+=256){
    int l=j>>4, c4=j&15;
    cat4[l*32+c4]    = xs4[j];
    cat4[l*32+16+c4] = xr4[j];
  }
  if (tid<25) s_wig0[tid]=wig[(size_t)e*475+tid];
  __syncthreads();
  if (tid<128){
    float acc=0;
    #pragma unroll
    for (int l=0;l<25;l++) acc += s_wig0[l]*s_cat[l*128+tid];
    s_msg0[tid]=acc*radb[(size_t)e*384+tid];
  }
  __syncthreads();
  if (tid<64){
    float acc=0;
    #pragma unroll
    for (int k=0;k<128;k++) acc += s_msg0[k]*so2W[k*64+tid];
    s_sh0[tid]=silu_f(acc);
  }
  __syncthreads();
  {
    float acc=0;
    #pragma unroll
    for (int o=0;o<64;o++) acc += s_sh0[o]*alphaW[o*256+tid];
    s_a[tid]=silu_f(acc)*alphaV[tid];
  }
  __syncthreads();
  if (tid<8){
    float lg=0;
    #pragma unroll
    for (int q=0;q<32;q++) lg += s_a[tid*32+q];
    logits[(size_t)e*8+tid]=lg;
    atomicMaxF(&mx[r*8+tid], lg);
  }
}

__global__ __launch_bounds__(256) void den_kernel(const float* __restrict__ logits,
    const float* __restrict__ mx, const int* __restrict__ rcv,
    float* __restrict__ den, int E){
  int idx = blockIdx.x*256+threadIdx.x;
  if (idx >= E*8) return;
  int e = idx>>3, hd = idx&7, r = rcv[e];
  atomicAdd(&den[r*8+hd], __expf(logits[idx]-mx[r*8+hd]));
}

// ---------------- pass 2, gather form: per node, loop in-edges ----------------
__global__ __launch_bounds__(256) void attn_gather_kernel(const float* __restrict__ xn,
    const float* __restrict__ wig, const float* __restrict__ winv, const float* __restrict__ radb,
    const float* __restrict__ so2W, const float* __restrict__ valW, const float* __restrict__ projW,
    const float* __restrict__ logits, const float* __restrict__ mx, const float* __restrict__ den,
    const int* __restrict__ snd, const int* __restrict__ rowptr, const int* __restrict__ eix,
    float* __restrict__ x, int N){
  int n = blockIdx.x, tid = threadIdx.x;
  __shared__ float s_cat[3200];   // [25][128] : cols 0..63 sender (per edge), 64..127 receiver (fixed)
  __shared__ float s_msg[2432];   // [19][128] msg -> v
  __shared__ float s_h[1216];     // [19][64]  h -> oe
  __shared__ float s_acc[1600];
  __shared__ float s_wig[475];
  __shared__ float s_winv[475];
  __shared__ float s_rad[384];
  __shared__ float s_attn[8];
  __shared__ int s_eix[MAXE];
  int row0=rowptr[n];
  int cnt=rowptr[n+1]-row0; if (cnt>MAXE) cnt=MAXE;
  {
    const float4* xr4=(const float4*)(xn+(size_t)n*1600);
    float4* cat4=(float4*)s_cat;
    for (int j=tid;j<400;j+=256){ int l=j>>4,c4=j&15; cat4[l*32+16+c4]=xr4[j]; }
    float4 z={0,0,0,0};
    for (int j=tid;j<400;j+=256) ((float4*)s_acc)[j]=z;
    for (int j=tid;j<cnt;j+=256) s_eix[j]=eix[row0+j];
  }
  __syncthreads();
  for (int le=0;le<cnt;le++){
    int e=s_eix[le];
    int s=snd[e];
    {
      const float4* xs4=(const float4*)(xn+(size_t)s*1600);
      float4* cat4=(float4*)s_cat;
      for (int j=tid;j<400;j+=256){ int l=j>>4,c4=j&15; cat4[l*32+c4]=xs4[l*16+c4]; }
    }
    for (int j=tid;j<475;j+=256){ s_wig[j]=wig[(size_t)e*475+j]; s_winv[j]=winv[(size_t)e*475+j]; }
    for (int j=tid;j<96;j+=256) ((float4*)s_rad)[j]=((const float4*)(radb+(size_t)e*384))[j];
    if (tid<8) s_attn[tid]=__expf(logits[(size_t)e*8+tid]-mx[n*8+tid])/(den[n*8+tid]+1e-12f);
    __syncthreads();
    // msg = wig-rotate(cat) * rad : [19][128]
    for (int sI=tid;sI<608;sI+=256){
      int m=sI>>5, k4=sI&31;
      const float* wr=s_wig+m*25;
      const float4* catp=(const float4*)s_cat;
      float4 acc={0,0,0,0};
      #pragma unroll
      for (int l=0;l<25;l++){
        float w=wr[l];
        float4 cv=catp[l*32+k4];
        acc.x+=w*cv.x; acc.y+=w*cv.y; acc.z+=w*cv.z; acc.w+=w*cv.w;
      }
      float4 rv=((const float4*)s_rad)[d_mg[m]*32+k4];
      acc.x*=rv.x; acc.y*=rv.y; acc.z*=rv.z; acc.w*=rv.w;
      ((float4*)s_msg)[m*32+k4]=acc;
    }
    __syncthreads();
    // so2: h[m][o], K=128 — 6 row-batches x 16 col-quads = 96 items
    for (int sI=tid;sI<96;sI+=256){
      int b=sI>>4, c4=sI&15;
      int g=d_bg[b], nr=d_bn[b];
      int r0=d_b4[b][0], r1=d_b4[b][1], r2=d_b4[b][2], r3=d_b4[b][3];
      const float4* W=(const float4*)(so2W+g*8192);
      const float4* M=(const float4*)s_msg;
      float4 c0={0,0,0,0},c1={0,0,0,0},c2={0,0,0,0},c3={0,0,0,0};
      for (int k4=0;k4<32;k4++){
        float4 a0=M[r0*32+k4], a1=M[r1*32+k4], a2=M[r2*32+k4], a3=M[r3*32+k4];
        float4 w0=W[(k4*4+0)*16+c4], w1=W[(k4*4+1)*16+c4], w2=W[(k4*4+2)*16+c4], w3=W[(k4*4+3)*16+c4];
        c0.x+=a0.x*w0.x+a0.y*w1.x+a0.z*w2.x+a0.w*w3.x;
        c0.y+=a0.x*w0.y+a0.y*w1.y+a0.z*w2.y+a0.w*w3.y;
        c0.z+=a0.x*w0.z+a0.y*w1.z+a0.z*w2.z+a0.w*w3.z;
        c0.w+=a0.x*w0.w+a0.y*w1.w+a0.z*w2.w+a0.w*w3.w;
        c1.x+=a1.x*w0.x+a1.y*w1.x+a1.z*w2.x+a1.w*w3.x;
        c1.y+=a1.x*w0.y+a1.y*w1.y+a1.z*w2.y+a1.w*w3.y;
        c1.z+=a1.x*w0.z+a1.y*w1.z+a1.z*w2.z+a1.w*w3.z;
        c1.w+=a1.x*w0.w+a1.y*w1.w+a1.z*w2.w+a1.w*w3.w;
        c2.x+=a2.x*w0.x+a2.y*w1.x+a2.z*w2.x+a2.w*w3.x;
        c2.y+=a2.x*w0.y+a2.y*w1.y+a2.z*w2.y+a2.w*w3.y;
        c2.z+=a2.x*w0.z+a2.y*w1.z+a2.z*w2.z+a2.w*w3.z;
        c2.w+=a2.x*w0.w+a2.y*w1.w+a2.z*w2.w+a2.w*w3.w;
        c3.x+=a3.x*w0.x+a3.y*w1.x+a3.z*w2.x+a3.w*w3.x;
        c3.y+=a3.x*w0.y+a3.y*w1.y+a3.z*w2.y+a3.w*w3.y;
        c3.z+=a3.x*w0.z+a3.y*w1.z+a3.z*w2.z+a3.w*w3.z;
        c3.w+=a3.x*w0.w+a3.y*w1.w+a3.z*w2.w+a3.w*w3.w;
      }
      float4* H=(float4*)s_h;
      H[r0*16+c4]=c0;
      if (nr>1) H[r1*16+c4]=c1;
      if (nr>2) H[r2*16+c4]=c2;
      if (nr>3) H[r3*16+c4]=c3;
    }
    __syncthreads();
    // val: v[m][jj]*attn, K=64 — 6 batches x 32 col-quads = 192 items (writes over s_msg)
    for (int sI=tid;sI<192;sI+=256){
      int b=sI>>5, c4=sI&31;
      int g=d_bg[b], nr=d_bn[b];
      int r0=d_b4[b][0], r1=d_b4[b][1], r2=d_b4[b][2], r3=d_b4[b][3];
      const float4* V=(const float4*)(valW+g*8192);
      const float4* H=(const float4*)s_h;
      float4 c0={0,0,0,0},c1={0,0,0,0},c2={0,0,0,0},c3={0,0,0,0};
      for (int k4=0;k4<16;k4++){
        float4 a0=H[r0*16+k4], a1=H[r1*16+k4], a2=H[r2*16+k4], a3=H[r3*16+k4];
        float4 w0=V[(k4*4+0)*32+c4], w1=V[(k4*4+1)*32+c4], w2=V[(k4*4+2)*32+c4], w3=V[(k4*4+3)*32+c4];
        c0.x+=a0.x*w0.x+a0.y*w1.x+a0.z*w2.x+a0.w*w3.x;
        c0.y+=a0.x*w0.y+a0.y*w1.y+a0.z*w2.y+a0.w*w3.y;
        c0.z+=a0.x*w0.z+a0.y*w1.z+a0.z*w2.z+a0.w*w3.z;
        c0.w+=a0.x*w0.w+a0.y*w1.w+a0.z*w2.w+a0.w*w3.w;
        c1.x+=a1.x*w0.x+a1.y*w1.x+a1.z*w2.x+a1.w*w3.x;
        c1.y+=a1.x*w0.y+a1.y*w1.y+a1.z*w2.y+a1.w*w3.y;
        c1.z+=a1.x*w0.z+a1.y*w1.z+a1.z*w2.z+a1.w*w3.z;
        c1.w+=a1.x*w0.w+a1.y*w1.w+a1.z*w2.w+a1.w*w3.w;
        c2.x+=a2.x*w0.x+a2.y*w1.x+a2.z*w2.x+a2.w*w3.x;
        c2.y+=a2.x*w0.y+a2.y*w1.y+a2.z*w2.y+a2.w*w3.y;
        c2.z+=a2.x*w0.z+a2.y*w1.z+a2.z*w2.z+a2.w*w3.z;
        c2.w+=a2.x*w0.w+a2.y*w1.w+a2.z*w2.w+a2.w*w3.w;
        c3.x+=a3.x*w0.x+a3.y*w1.x+a3.z*w2.x+a3.w*w3.x;
        c3.y+=a3.x*w0.y+a3.y*w1.y+a3.z*w2.y+a3.w*w3.y;
        c3.z+=a3.x*w0.z+a3.y*w1.z+a3.z*w2.z+a3.w*w3.z;
        c3.w+=a3.x*w0.w+a3.y*w1.w+a3.z*w2.w+a3.w*w3.w;
      }
      float a=s_attn[c4>>2];
      c0.x*=a;c0.y*=a;c0.z*=a;c0.w*=a;
      c1.x*=a;c1.y*=a;c1.z*=a;c1.w*=a;
      c2.x*=a;c2.y*=a;c2.z*=a;c2.w*=a;
      c3.x*=a;c3.y*=a;c3.z*=a;c3.w*=a;
      float4* VV=(float4*)s_msg;
      VV[r0*32+c4]=c0;
      if (nr>1) VV[r1*32+c4]=c1;
      if (nr>2) VV[r2*32+c4]=c2;
      if (nr>3) VV[r3*32+c4]=c3;
    }
    __syncthreads();
    // proj: oe[m][c], K=128 — 96 items (reads s_msg=v, writes over s_h)
    for (int sI=tid;sI<96;sI+=256){
      int b=sI>>4, c4=sI&15;
      int g=d_bg[b], nr=d_bn[b];
      int r0=d_b4[b][0], r1=d_b4[b][1], r2=d_b4[b][2], r3=d_b4[b][3];
      const float4* P=(const float4*)(projW+g*8192);
      const float4* Vp=(const float4*)s_msg;
      float4 c0={0,0,0,0},c1={0,0,0,0},c2={0,0,0,0},c3={0,0,0,0};
      for (int k4=0;k4<32;k4++){
        float4 a0=Vp[r0*32+k4], a1=Vp[r1*32+k4], a2=Vp[r2*32+k4], a3=Vp[r3*32+k4];
        float4 w0=P[(k4*4+0)*16+c4], w1=P[(k4*4+1)*16+c4], w2=P[(k4*4+2)*16+c4], w3=P[(k4*4+3)*16+c4];
        c0.x+=a0.x*w0.x+a0.y*w1.x+a0.z*w2.x+a0.w*w3.x;
        c0.y+=a0.x*w0.y+a0.y*w1.y+a0.z*w2.y+a0.w*w3.y;
        c0.z+=a0.x*w0.z+a0.y*w1.z+a0.z*w2.z+a0.w*w3.z;
        c0.w+=a0.x*w0.w+a0.y*w1.w+a0.z*w2.w+a0.w*w3.w;
        c1.x+=a1.x*w0.x+a1.y*w1.x+a1.z*w2.x+a1.w*w3.x;
        c1.y+=a1.x*w0.y+a1.y*w1.y+a1.z*w2.y+a1.w*w3.y;
        c1.z+=a1.x*w0.z+a1.y*w1.z+a1.z*w2.z+a1.w*w3.z;
        c1.w+=a1.x*w0.w+a1.y*w1.w+a1.z*w2.w+a1.w*w3.w;
        c2.x+=a2.x*w0.x+a2.y*w1.x+a2.z*w2.x+a2.w*w3.x;
        c2.y+=a2.x*w0.y+a2.y*w1.y+a2.z*w2.y+a2.w*w3.y;
        c2.z+=a2.x*w0.z+a2.y*w1.z+a2.z*w2.z+a2.w*w3.z;
        c2.w+=a2.x*w0.w+a2.y*w1.w+a2.z*w2.w+a2.w*w3.w;
        c3.x+=a3.x*w0.x+a3.y*w1.x+a3.z*w2.x+a3.w*w3.x;
        c3.y+=a3.x*w0.y+a3.y*w1.y+a3.z*w2.y+a3.w*w3.y;
        c3.z+=a3.x*w0.z+a3.y*w1.z+a3.z*w2.z+a3.w*w3.z;
        c3.w+=a3.x*w0.w+a3.y*w1.w+a3.z*w2.w+a3.w*w3.w;
      }
      float4* OE=(float4*)s_h;
      OE[r0*16+c4]=c0;
      if (nr>1) OE[r1*16+c4]=c1;
      if (nr>2) OE[r2*16+c4]=c2;
      if (nr>3) OE[r3*16+c4]=c3;
    }
    __syncthreads();
    // rotate back (winv) + accumulate in LDS
    for (int sI=tid;sI<400;sI+=256){
      int l=sI>>4, c4=sI&15;
      const float* wr=s_winv+l*19;
      const float4* OE=(const float4*)s_h;
      float4 acc={0,0,0,0};
      #pragma unroll
      for (int m=0;m<19;m++){
        float w=wr[m];
        float4 ov=OE[m*16+c4];
        acc.x+=w*ov.x; acc.y+=w*ov.y; acc.z+=w*ov.z; acc.w+=w*ov.w;
      }
      float4* A=(float4*)s_acc;
      float4 cur=A[sI];
      cur.x+=acc.x; cur.y+=acc.y; cur.z+=acc.z; cur.w+=acc.w;
      A[sI]=cur;
    }
    __syncthreads();
  }
  // x[n] += acc (residual already in x)
  float4* xp=(float4*)(x+(size_t)n*1600);
  for (int j=tid;j<400;j+=256){
    float4 cur=xp[j];
    float4 av=((float4*)s_acc)[j];
    cur.x+=av.x; cur.y+=av.y; cur.z+=av.z; cur.w+=av.w;
    xp[j]=cur;
  }
}

// ---------------- S2 grid FFN ----------------
__global__ __launch_bounds__(256) void grid_ffn_kernel(const float* __restrict__ xn,
    const float* __restrict__ tg, const float* __restrict__ fg,
    const float* __restrict__ W1, const float* __restrict__ b1, const float* __restrict__ W2,
    float* __restrict__ x, int N){
  int n = blockIdx.x, tid = threadIdx.x;
  __shared__ float s_xn[1600];
  __shared__ float s_W2[8192];
  __shared__ float s_b1[128];
  __shared__ float s_g[4][64];
  __shared__ float s_hid[4][128];
  __shared__ float s_o[4][64];
  const float* xr = xn + (size_t)n*1600;
  for (int j=tid;j<1600;j+=256) s_xn[j]=xr[j];
  {
    const float4* src=(const float4*)W2;
    float4* dst=(float4*)s_W2;
    for (int j=tid;j<2048;j+=256) dst[j]=src[j];
  }
  if (tid<128) s_b1[tid]=b1[tid];
  float accv[7];
  #pragma unroll
  for (int t=0;t<7;t++) accv[t]=0.0f;
  __syncthreads();
  for (int gp=0; gp<GPTS; gp+=4){
    int gpl=tid>>6, c=tid&63;
    {
      float a=0;
      #pragma unroll
      for (int l=0;l<25;l++) a += tg[(gp+gpl)*25+l]*s_xn[l*64+c];
      s_g[gpl][c]=a;
    }
    __syncthreads();
    {
      int hh=tid&127, gh=tid>>7;
      #pragma unroll
      for (int q=0;q<2;q++){
        int gg=gh+2*q;
        float h=s_b1[hh];
        #pragma unroll
        for (int cc=0;cc<64;cc++) h += s_g[gg][cc]*W1[cc*128+hh];
        s_hid[gg][hh]=silu_f(h);
      }
    }
    __syncthreads();
    {
      float o=0;
      #pragma unroll
      for (int hh=0;hh<128;hh++) o += s_hid[gpl][hh]*s_W2[hh*64+c];
      s_o[gpl][c]=o;
    }
    __syncthreads();
    {
      int t=0;
      for (int idx=tid; idx<1600; idx+=256, t++){
        int l=idx>>6, cc=idx&63;
        float s=0;
        #pragma unroll
        for (int g2=0; g2<4; g2++) s += fg[l*288+gp+g2]*s_o[g2][cc];
        accv[t]+=s;
      }
    }
    __syncthreads();
  }
  {
    int t=0;
    for (int idx=tid; idx<1600; idx+=256, t++) x[(size_t)n*1600+idx] += accv[t];
  }
}

// ---------------- final energy head ----------------
__global__ __launch_bounds__(256) void energy_kernel(const float* __restrict__ xn,
    const float* __restrict__ tg, const float* __restrict__ fg,
    const float* __restrict__ W1, const float* __restrict__ b1,
    const float* __restrict__ W2, const float* __restrict__ b2,
    float* __restrict__ out, int N){
  int n = blockIdx.x, tid = threadIdx.x;
  __shared__ float s_xn[1600];
  __shared__ float s_W1[8192];
  __shared__ float s_b1[128];
  __shared__ float s_w2[128];
  __shared__ float s_g[4][64];
  __shared__ float s_hid[4][128];
  __shared__ float s_red[4][64];
  const float* xr = xn + (size_t)n*1600;
  for (int j=tid;j<1600;j+=256) s_xn[j]=xr[j];
  {
    const float4* src=(const float4*)W1;
    float4* dst=(float4*)s_W1;
    for (int j=tid;j<2048;j+=256) dst[j]=src[j];
  }
  if (tid<128){ s_b1[tid]=b1[tid]; s_w2[tid]=W2[tid]; }
  float b2v = b2[0];
  float priv = 0.0f;
  __syncthreads();
  for (int gp=0; gp<GPTS; gp+=4){
    int gpl=tid>>6, c=tid&63;
    {
      float a=0;
      #pragma unroll
      for (int l=0;l<25;l++) a += tg[(gp+gpl)*25+l]*s_xn[l*64+c];
      s_g[gpl][c]=a;
    }
    __syncthreads();
    {
      int hh=tid&127, gh=tid>>7;
      #pragma unroll
      for (int q=0;q<2;q++){
        int gg=gh+2*q;
        float h=s_b1[hh];
        #pragma unroll
        for (int cc=0;cc<64;cc++) h += s_g[gg][cc]*s_W1[cc*128+hh];
        s_hid[gg][hh]=silu_f(h);
      }
    }
    __syncthreads();
    {
      float part = s_hid[gpl][c]*s_w2[c] + s_hid[gpl][c+64]*s_w2[c+64];
      s_red[gpl][c]=part;
    }
    __syncthreads();
    if (tid<4){
      float sum=0;
      #pragma unroll
      for (int q=0;q<64;q++) sum += s_red[tid][q];
      priv += fg[gp+tid]*(sum+b2v);
    }
    __syncthreads();
  }
  if (tid<4) s_red[0][tid]=priv;
  __syncthreads();
  if (tid==0) out[n]=(s_red[0][0]+s_red[0][1]+s_red[0][2]+s_red[0][3])*(1.0f/2000.0f);
}

extern "C" void kernel_launch(void* const* d_in, const int* in_sizes, int n_in,
                              void* d_out, int out_size, void* d_ws, size_t ws_size,
                              hipStream_t stream){
  (void)n_in; (void)out_size; (void)ws_size;
  const float* ev   = (const float*)d_in[0];
  const float* wig  = (const float*)d_in[1];
  const float* winv = (const float*)d_in[2];
  const float* spe  = (const float*)d_in[3];
  const float* ese  = (const float*)d_in[4];
  const float* degW1= (const float*)d_in[5];
  const float* degb1= (const float*)d_in[6];
  const float* degW2= (const float*)d_in[7];
  const float* degb2= (const float*)d_in[8];
  const float* n1w  = (const float*)d_in[9];
  const float* radW1= (const float*)d_in[10];
  const float* radb1= (const float*)d_in[11];
  const float* radW2= (const float*)d_in[12];
  const float* radb2= (const float*)d_in[13];
  const float* so2W = (const float*)d_in[14];
  const float* aW   = (const float*)d_in[15];
  const float* aV   = (const float*)d_in[16];
  const float* vW   = (const float*)d_in[17];
  const float* pW   = (const float*)d_in[18];
  const float* n2w  = (const float*)d_in[19];
  const float* fW1  = (const float*)d_in[20];
  const float* fb1  = (const float*)d_in[21];
  const float* fW2  = (const float*)d_in[22];
  const float* tg   = (const float*)d_in[23];
  const float* fg   = (const float*)d_in[24];
  const float* fnw  = (const float*)d_in[25];
  const float* enW1 = (const float*)d_in[26];
  const float* enb1 = (const float*)d_in[27];
  const float* enW2 = (const float*)d_in[28];
  const float* enb2 = (const float*)d_in[29];
  const int* nsp = (const int*)d_in[30];
  const int* snd = (const int*)d_in[31];
  const int* rcv = (const int*)d_in[32];
  int N = in_sizes[30];
  int E = in_sizes[31];
  float* out = (float*)d_out;

  float* ws = (float*)d_ws;
  size_t off = 0;
  float* radbuf = ws + off; off += (size_t)E*384;
  float* logits = ws + off; off += (size_t)E*8;
  float* mx     = ws + off; off += (size_t)N*8;
  float* den    = ws + off; off += (size_t)N*8;
  float* x      = ws + off; off += (size_t)N*1600;
  float* xn     = ws + off; off += (size_t)N*1600;
  int* cnt      = (int*)(ws + off); off += (size_t)N;
  int* rowptr   = (int*)(ws + off); off += (size_t)(N+1);
  int* fill     = (int*)(ws + off); off += (size_t)N;
  int* eixbuf   = (int*)(ws + off); off += (size_t)E;

  // CSR by receiver
  zero_cnt_kernel<<<(N+255)/256, 256, 0, stream>>>(cnt, N);
  csr_count_kernel<<<(E+255)/256, 256, 0, stream>>>(rcv, cnt, E);
  csr_scan_kernel<<<1, 256, 0, stream>>>(cnt, rowptr, fill, N);
  csr_fill_kernel<<<(E+255)/256, 256, 0, stream>>>(rcv, fill, eixbuf, E);

  deg_gather_kernel<<<N, 256, 0, stream>>>(ev, ese, nsp, spe, degW1, degb1, degW2, degb2,
                                           winv, snd, rowptr, eixbuf, x, N);

  for (int i=0;i<2;i++){
    rmsnorm_kernel<<<N, 256, 0, stream>>>(x, n1w + (size_t)i*320, xn, N);
    init_mxden_kernel<<<(N*8+255)/256, 256, 0, stream>>>(mx, den, N);
    rad_kernel<<<(E+3)/4, 256, 0, stream>>>(ev, ese, nsp, radW1 + (size_t)i*DIN*128, radb1 + (size_t)i*128,
                                            radW2 + (size_t)i*128*384, radb2 + (size_t)i*384,
                                            snd, rcv, radbuf, E);
    logits_kernel<<<E, 256, 0, stream>>>(xn, wig, radbuf, so2W + (size_t)i*3*8192,
                                         aW + (size_t)i*64*256, aV + (size_t)i*256,
                                         snd, rcv, logits, mx, E);
    den_kernel<<<(E*8+255)/256, 256, 0, stream>>>(logits, mx, rcv, den, E);
    attn_gather_kernel<<<N, 256, 0, stream>>>(xn, wig, winv, radbuf, so2W + (size_t)i*3*8192,
                                              vW + (size_t)i*3*8192, pW + (size_t)i*3*8192,
                                              logits, mx, den, snd, rowptr, eixbuf, x, N);
    rmsnorm_kernel<<<N, 256, 0, stream>>>(x, n2w + (size_t)i*320, xn, N);
    grid_ffn_kernel<<<N, 256, 0, stream>>>(xn, tg, fg, fW1 + (size_t)i*8192, fb1 + (size_t)i*128,
                                           fW2 + (size_t)i*8192, x, N);
  }
  rmsnorm_kernel<<<N, 256, 0, stream>>>(x, fnw, xn, N);
  energy_kernel<<<N, 256, 0, stream>>>(xn, tg, fg, enW1, enb1, enW2, enb2, out, N);
}